// Round 2
// baseline (502.332 us; speedup 1.0000x reference)
//
#include <hip/hip_runtime.h>

typedef unsigned short u16;
typedef __attribute__((ext_vector_type(8))) short short8;
typedef __attribute__((ext_vector_type(4))) float f32x4;

#define N_NODES 50000
#define N_EDGES 800000
#define DIM 128
#define SCAN_B 196   /* ceil(50000/256) */

__device__ __forceinline__ float bf2f(u16 u) {
    union { unsigned int i; float f; } v; v.i = ((unsigned int)u) << 16; return v.f;
}
__device__ __forceinline__ u16 f2bf(float f) {
    union { float f; unsigned int i; } v; v.f = f;
    return (u16)((v.i + 0x7FFFu + ((v.i >> 16) & 1u)) >> 16);
}
// split f into bf16 hi + bf16 lo (hi = rn(f), lo = rn(f - hi)); hi+lo ≈ f to ~2^-17 rel
__device__ __forceinline__ void split_bf(float f, u16& hi, u16& lo) {
    hi = f2bf(f);
    lo = f2bf(f - bf2f(hi));
}

// ---------------- CSR build ----------------

__global__ void k_deg_hist(const int* __restrict__ dst, int* __restrict__ deg) {
    int e = blockIdx.x * 256 + threadIdx.x;
    if (e < N_EDGES) atomicAdd(&deg[dst[e]], 1);
}

__global__ void k_scan1(const int* __restrict__ deg, int* __restrict__ bsum) {
    __shared__ int sd[256];
    int t = threadIdx.x; int i = blockIdx.x * 256 + t;
    sd[t] = (i < N_NODES) ? deg[i] : 0;
    __syncthreads();
    for (int o = 128; o > 0; o >>= 1) { if (t < o) sd[t] += sd[t + o]; __syncthreads(); }
    if (t == 0) bsum[blockIdx.x] = sd[0];
}

__global__ void k_scan2(const int* __restrict__ bsum, int* __restrict__ bpre) {
    __shared__ int sd[256];
    int t = threadIdx.x;
    int v = (t < SCAN_B) ? bsum[t] : 0;
    sd[t] = v; __syncthreads();
    for (int o = 1; o < 256; o <<= 1) {
        int x = sd[t] + ((t >= o) ? sd[t - o] : 0);
        __syncthreads(); sd[t] = x; __syncthreads();
    }
    if (t < SCAN_B) bpre[t] = sd[t] - v;   // exclusive
}

__global__ void k_scan3(const int* __restrict__ deg, const int* __restrict__ bpre,
                        int* __restrict__ row_ptr) {
    __shared__ int sd[256];
    int t = threadIdx.x; int i = blockIdx.x * 256 + t;
    int v = (i < N_NODES) ? deg[i] : 0;
    sd[t] = v; __syncthreads();
    for (int o = 1; o < 256; o <<= 1) {
        int x = sd[t] + ((t >= o) ? sd[t - o] : 0);
        __syncthreads(); sd[t] = x; __syncthreads();
    }
    if (i <= N_NODES) row_ptr[i] = bpre[blockIdx.x] + sd[t] - v;  // i==N gets E
}

__global__ void k_fill(const int* __restrict__ src, const int* __restrict__ dst,
                       const int* __restrict__ row_ptr, int* __restrict__ cursor,
                       int* __restrict__ col_src) {
    int e = blockIdx.x * 256 + threadIdx.x;
    if (e < N_EDGES) {
        int d = dst[e];
        int pos = row_ptr[d] + atomicAdd(&cursor[d], 1);
        col_src[pos] = src[e];
    }
}

// ---------------- aggregation (mean of source rows per dst node), fp32 ----------------

__global__ void k_agg(const float* __restrict__ feat, const int* __restrict__ row_ptr,
                      const int* __restrict__ col_src, float* __restrict__ outv) {
    int node = blockIdx.x; int d = threadIdx.x;      // 128 threads
    int s = row_ptr[node], e = row_ptr[node + 1];
    float sum = 0.f;
    for (int j = s; j < e; ++j) {
        int sr = col_src[j];
        sum += feat[(long)sr * DIM + d];
    }
    float dn = (e > s) ? (float)(e - s) : 1.f;
    outv[(long)node * DIM + d] = sum / dn;
}

// ---------------- B packing for MFMA fragment order (split hi/lo bf16) ----------------
// Bp*[((nt*8+kc)*64 + lane)*8 + j] = B[kc*32 + (lane>>4)*8 + j][nt*16 + (lane&15)]
// where B = [Wl; Wr] stacked (256 x 128), fp32 input.
__global__ void k_pack_b(const float* __restrict__ Wl, const float* __restrict__ Wr,
                         u16* __restrict__ Bph, u16* __restrict__ Bpl) {
    int idx = blockIdx.x * 256 + threadIdx.x;        // 4096 total
    if (idx >= 8 * 8 * 64) return;
    int lane = idx & 63;
    int kc = (idx >> 6) & 7;
    int nt = idx >> 9;
    int q = lane >> 4, nn = lane & 15;
    int col = nt * 16 + nn;
    #pragma unroll
    for (int j = 0; j < 8; ++j) {
        int k = kc * 32 + q * 8 + j;
        float v = (k < 128) ? Wl[k * 128 + col] : Wr[(k - 128) * 128 + col];
        u16 hi, lo; split_bf(v, hi, lo);
        Bph[(long)idx * 8 + j] = hi;
        Bpl[(long)idx * 8 + j] = lo;
    }
}

// ---------------- fused GEMM: out = [Al | Ar](N x 256) @ B(256 x 128) + bias ----------------
// MFMA 16x16x32 bf16, split-precision: D = Ah*Bh + Ah*Bl + Al*Bh (~fp32 accurate).
// Block = 256 thr = 4 waves; block covers 64 rows, wave 16 rows x 128 cols.
// A-frag: lane holds A[m=lane&15][k=(lane>>4)*8+j]; C/D: col=lane&15, row=(lane>>4)*4+reg.
__global__ __launch_bounds__(256) void k_gemm(
        const float* __restrict__ Al, const float* __restrict__ Ar,
        const u16* __restrict__ Bph, const u16* __restrict__ Bpl,
        const float* __restrict__ bias,
        float* __restrict__ outH, int nrows) {
    int tid = threadIdx.x;
    int wave = tid >> 6, lane = tid & 63;
    int q = lane >> 4, nn = lane & 15;
    int rowbase = blockIdx.x * 64 + wave * 16;
    int arow = rowbase + nn;
    int rclamp = (arow < nrows) ? arow : 0;

    f32x4 acc[8];
    #pragma unroll
    for (int i = 0; i < 8; ++i) acc[i] = (f32x4){0.f, 0.f, 0.f, 0.f};

    #pragma unroll
    for (int kc = 0; kc < 8; ++kc) {
        const float* ap = (kc < 4) ? (Al + (long)rclamp * DIM + kc * 32 + q * 8)
                                   : (Ar + (long)rclamp * DIM + (kc - 4) * 32 + q * 8);
        f32x4 a0 = *(const f32x4*)ap;
        f32x4 a1 = *(const f32x4*)(ap + 4);
        short8 ah, al;
        #pragma unroll
        for (int j = 0; j < 4; ++j) {
            u16 hi, lo;
            split_bf(a0[j], hi, lo); ah[j] = (short)hi; al[j] = (short)lo;
            split_bf(a1[j], hi, lo); ah[4 + j] = (short)hi; al[4 + j] = (short)lo;
        }
        #pragma unroll
        for (int nt = 0; nt < 8; ++nt) {
            long boff = (long)(((nt * 8 + kc) * 64 + lane)) * 8;
            short8 bh = *(const short8*)(Bph + boff);
            short8 bl = *(const short8*)(Bpl + boff);
            acc[nt] = __builtin_amdgcn_mfma_f32_16x16x32_bf16(ah, bh, acc[nt], 0, 0, 0);
            acc[nt] = __builtin_amdgcn_mfma_f32_16x16x32_bf16(ah, bl, acc[nt], 0, 0, 0);
            acc[nt] = __builtin_amdgcn_mfma_f32_16x16x32_bf16(al, bh, acc[nt], 0, 0, 0);
        }
    }

    #pragma unroll
    for (int nt = 0; nt < 8; ++nt) {
        int col = nt * 16 + nn;
        float bv = bias[col];
        #pragma unroll
        for (int r = 0; r < 4; ++r) {
            int orow = rowbase + q * 4 + r;
            if (orow < nrows) outH[(long)orow * DIM + col] = acc[nt][r] + bv;
        }
    }
}

// ---------------- BN column stats: sums[c] = sum h[:,c]; sums[128+c] = sum h[:,c]^2 ----------------
__global__ void k_colstats(const float* __restrict__ h, float* __restrict__ sums) {
    int c = threadIdx.x & 127;
    int half = threadIdx.x >> 7;
    float s = 0.f, qq = 0.f;
    for (int r = blockIdx.x * 2 + half; r < N_NODES; r += gridDim.x * 2) {
        float v = h[(long)r * DIM + c];
        s += v; qq += v * v;
    }
    __shared__ float red[256];
    red[threadIdx.x] = s; __syncthreads();
    if (half == 0) atomicAdd(&sums[c], s + red[threadIdx.x + 128]);
    __syncthreads();
    red[threadIdx.x] = qq; __syncthreads();
    if (half == 0) atomicAdd(&sums[128 + c], qq + red[threadIdx.x + 128]);
}

// ac[c] = g/sqrt(var+eps); ac[128+c] = bt - mu*ac[c]
__global__ void k_bn_coeff(const float* __restrict__ sums, const float* __restrict__ g,
                           const float* __restrict__ bt, float* __restrict__ ac) {
    int c = threadIdx.x;  // 128
    const float ninv = 1.0f / (float)N_NODES;
    float mu = sums[c] * ninv;
    float var = sums[128 + c] * ninv - mu * mu;
    float a = g[c] * rsqrtf(var + 1e-5f);
    ac[c] = a;
    ac[128 + c] = bt[c] - mu * a;
}

// h = relu(h*a + c)  (in place)
__global__ void k_bn_relu(float* __restrict__ h, const float* __restrict__ ac) {
    long i = (long)blockIdx.x * 256 + threadIdx.x;
    if (i < (long)N_NODES * DIM) {
        int c = (int)(i & 127);
        float v = h[i] * ac[c] + ac[128 + c];
        h[i] = v > 0.f ? v : 0.f;
    }
}

// out = relu(h*a + c + x)
__global__ void k_bn_add_relu(const float* __restrict__ h, const float* __restrict__ ac,
                              const float* __restrict__ x, float* __restrict__ outv) {
    long i = (long)blockIdx.x * 256 + threadIdx.x;
    if (i < (long)N_NODES * DIM) {
        int c = (int)(i & 127);
        float v = h[i] * ac[c] + ac[128 + c] + x[i];
        outv[i] = v > 0.f ? v : 0.f;
    }
}

extern "C" void kernel_launch(void* const* d_in, const int* in_sizes, int n_in,
                              void* d_out, int out_size, void* d_ws, size_t ws_size,
                              hipStream_t stream) {
    (void)in_sizes; (void)n_in; (void)out_size; (void)ws_size;
    const float* x   = (const float*)d_in[0];
    const int*   ei  = (const int*)d_in[1];
    const float* W1l = (const float*)d_in[2];
    const float* b1  = (const float*)d_in[3];
    const float* W1r = (const float*)d_in[4];
    const float* g1  = (const float*)d_in[5];
    const float* bt1 = (const float*)d_in[6];
    const float* W2l = (const float*)d_in[7];
    const float* b2  = (const float*)d_in[8];
    const float* W2r = (const float*)d_in[9];
    const float* g2  = (const float*)d_in[10];
    const float* bt2 = (const float*)d_in[11];
    float* out = (float*)d_out;

    const int* esrc = ei;
    const int* edst = ei + N_EDGES;

    char* ws = (char*)d_ws;
    size_t off = 0;
    auto alloc = [&](size_t bytes) { size_t p = off; off = (off + bytes + 255) & ~(size_t)255; return p; };
    int*   deg     = (int*)  (ws + alloc(N_NODES * 4));
    int*   cursor  = (int*)  (ws + alloc(N_NODES * 4));
    float* stats1  = (float*)(ws + alloc(256 * 4));
    float* stats2  = (float*)(ws + alloc(256 * 4));
    size_t zero_bytes = off;                       // everything above must be zeroed
    float* ac1     = (float*)(ws + alloc(256 * 4));
    float* ac2     = (float*)(ws + alloc(256 * 4));
    int*   row_ptr = (int*)  (ws + alloc((N_NODES + 1) * 4));
    int*   bsum    = (int*)  (ws + alloc(256 * 4));
    int*   bpre    = (int*)  (ws + alloc(256 * 4));
    int*   col_src = (int*)  (ws + alloc((size_t)N_EDGES * 4));
    float* aggbuf  = (float*)(ws + alloc((size_t)N_NODES * DIM * 4));
    float* hbuf    = (float*)(ws + alloc((size_t)N_NODES * DIM * 4));
    u16*   Bp1h    = (u16*)  (ws + alloc(256 * 128 * 2));
    u16*   Bp1l    = (u16*)  (ws + alloc(256 * 128 * 2));
    u16*   Bp2h    = (u16*)  (ws + alloc(256 * 128 * 2));
    u16*   Bp2l    = (u16*)  (ws + alloc(256 * 128 * 2));

    hipMemsetAsync(ws, 0, zero_bytes, stream);

    const int EB = (N_EDGES + 255) / 256;            // 3125
    const int GEMMB = (N_NODES + 63) / 64;           // 782
    const long TOT = (long)N_NODES * DIM;
    const int EWB = (int)((TOT + 255) / 256);        // 25000

    // weight packing (independent of everything else)
    k_pack_b<<<16, 256, 0, stream>>>(W1l, W1r, Bp1h, Bp1l);
    k_pack_b<<<16, 256, 0, stream>>>(W2l, W2r, Bp2h, Bp2l);

    // CSR build
    k_deg_hist<<<EB, 256, 0, stream>>>(edst, deg);
    k_scan1<<<SCAN_B, 256, 0, stream>>>(deg, bsum);
    k_scan2<<<1, 256, 0, stream>>>(bsum, bpre);
    k_scan3<<<SCAN_B, 256, 0, stream>>>(deg, bpre, row_ptr);
    k_fill<<<EB, 256, 0, stream>>>(esrc, edst, row_ptr, cursor, col_src);

    // stage 1
    k_agg<<<N_NODES, 128, 0, stream>>>(x, row_ptr, col_src, aggbuf);
    k_gemm<<<GEMMB, 256, 0, stream>>>(aggbuf, x, Bp1h, Bp1l, b1, hbuf, N_NODES);
    k_colstats<<<256, 256, 0, stream>>>(hbuf, stats1);
    k_bn_coeff<<<1, 128, 0, stream>>>(stats1, g1, bt1, ac1);
    k_bn_relu<<<EWB, 256, 0, stream>>>(hbuf, ac1);

    // stage 2 (hbuf now holds h1r; gemm writes h2 in place — wave-private rows, reads precede writes)
    k_agg<<<N_NODES, 128, 0, stream>>>(hbuf, row_ptr, col_src, aggbuf);
    k_gemm<<<GEMMB, 256, 0, stream>>>(aggbuf, hbuf, Bp2h, Bp2l, b2, hbuf, N_NODES);
    k_colstats<<<256, 256, 0, stream>>>(hbuf, stats2);
    k_bn_coeff<<<1, 128, 0, stream>>>(stats2, g2, bt2, ac2);
    k_bn_add_relu<<<EWB, 256, 0, stream>>>(hbuf, ac2, x, out);
}

// Round 3
// 419.486 us; speedup vs baseline: 1.1975x; 1.1975x over previous
//
#include <hip/hip_runtime.h>

typedef unsigned short u16;
typedef __attribute__((ext_vector_type(8))) short short8;
typedef __attribute__((ext_vector_type(4))) float f32x4;

#define N_NODES 50000
#define N_EDGES 800000
#define DIM 128
#define SCAN_B 196   /* ceil(50000/256) */
#define NINV (1.0f / 50000.0f)

__device__ __forceinline__ float bf2f(u16 u) {
    union { unsigned int i; float f; } v; v.i = ((unsigned int)u) << 16; return v.f;
}
__device__ __forceinline__ u16 f2bf(float f) {
    union { float f; unsigned int i; } v; v.f = f;
    return (u16)((v.i + 0x7FFFu + ((v.i >> 16) & 1u)) >> 16);
}
__device__ __forceinline__ void split_bf(float f, u16& hi, u16& lo) {
    hi = f2bf(f);
    lo = f2bf(f - bf2f(hi));
}

// ---------------- CSR build ----------------

__global__ void k_deg_hist(const int* __restrict__ dst, int* __restrict__ deg) {
    int e = blockIdx.x * 256 + threadIdx.x;
    if (e < N_EDGES) atomicAdd(&deg[dst[e]], 1);
}

__global__ void k_scan1(const int* __restrict__ deg, int* __restrict__ bsum) {
    __shared__ int sd[256];
    int t = threadIdx.x; int i = blockIdx.x * 256 + t;
    sd[t] = (i < N_NODES) ? deg[i] : 0;
    __syncthreads();
    for (int o = 128; o > 0; o >>= 1) { if (t < o) sd[t] += sd[t + o]; __syncthreads(); }
    if (t == 0) bsum[blockIdx.x] = sd[0];
}

__global__ void k_scan2(const int* __restrict__ bsum, int* __restrict__ bpre) {
    __shared__ int sd[256];
    int t = threadIdx.x;
    int v = (t < SCAN_B) ? bsum[t] : 0;
    sd[t] = v; __syncthreads();
    for (int o = 1; o < 256; o <<= 1) {
        int x = sd[t] + ((t >= o) ? sd[t - o] : 0);
        __syncthreads(); sd[t] = x; __syncthreads();
    }
    if (t < SCAN_B) bpre[t] = sd[t] - v;   // exclusive
}

__global__ void k_scan3(const int* __restrict__ deg, const int* __restrict__ bpre,
                        int* __restrict__ row_ptr) {
    __shared__ int sd[256];
    int t = threadIdx.x; int i = blockIdx.x * 256 + t;
    int v = (i < N_NODES) ? deg[i] : 0;
    sd[t] = v; __syncthreads();
    for (int o = 1; o < 256; o <<= 1) {
        int x = sd[t] + ((t >= o) ? sd[t - o] : 0);
        __syncthreads(); sd[t] = x; __syncthreads();
    }
    if (i <= N_NODES) row_ptr[i] = bpre[blockIdx.x] + sd[t] - v;  // i==N gets E
}

__global__ void k_fill(const int* __restrict__ src, const int* __restrict__ dst,
                       const int* __restrict__ row_ptr, int* __restrict__ cursor,
                       int* __restrict__ col_src) {
    int e = blockIdx.x * 256 + threadIdx.x;
    if (e < N_EDGES) {
        int d = dst[e];
        int pos = row_ptr[d] + atomicAdd(&cursor[d], 1);
        col_src[pos] = src[e];
    }
}

// ---------------- aggregation: mean of source rows per dst node ----------------
// 32 lanes per node, float4 per lane (16B x 32 = 512B = full row per load instr).
// 4x unrolled -> >=4 independent row loads in flight per group.
__global__ __launch_bounds__(256) void k_agg(
        const float* __restrict__ feat, const int* __restrict__ row_ptr,
        const int* __restrict__ col_src, float* __restrict__ outv) {
    int tid = threadIdx.x;
    int grp = tid >> 5;          // 0..7
    int g   = tid & 31;
    int node = blockIdx.x * 8 + grp;     // grid = 6250 -> exactly 50000
    int s = row_ptr[node], e = row_ptr[node + 1];
    f32x4 sum = (f32x4){0.f, 0.f, 0.f, 0.f};
    int j = s;
    for (; j + 4 <= e; j += 4) {
        int i0 = col_src[j], i1 = col_src[j + 1], i2 = col_src[j + 2], i3 = col_src[j + 3];
        f32x4 v0 = *(const f32x4*)(feat + (long)i0 * DIM + g * 4);
        f32x4 v1 = *(const f32x4*)(feat + (long)i1 * DIM + g * 4);
        f32x4 v2 = *(const f32x4*)(feat + (long)i2 * DIM + g * 4);
        f32x4 v3 = *(const f32x4*)(feat + (long)i3 * DIM + g * 4);
        sum += (v0 + v1) + (v2 + v3);
    }
    for (; j < e; ++j) {
        int i0 = col_src[j];
        sum += *(const f32x4*)(feat + (long)i0 * DIM + g * 4);
    }
    float dn = (e > s) ? (float)(e - s) : 1.f;
    f32x4 r;
    r[0] = sum[0] / dn; r[1] = sum[1] / dn; r[2] = sum[2] / dn; r[3] = sum[3] / dn;
    *(f32x4*)(outv + (long)node * DIM + g * 4) = r;
}

// ---------------- B packing for MFMA fragment order (split hi/lo bf16) ----------------
__global__ void k_pack_b(const float* __restrict__ Wl, const float* __restrict__ Wr,
                         u16* __restrict__ Bph, u16* __restrict__ Bpl) {
    int idx = blockIdx.x * 256 + threadIdx.x;        // 4096 total
    if (idx >= 8 * 8 * 64) return;
    int lane = idx & 63;
    int kc = (idx >> 6) & 7;
    int nt = idx >> 9;
    int q = lane >> 4, nn = lane & 15;
    int col = nt * 16 + nn;
    #pragma unroll
    for (int j = 0; j < 8; ++j) {
        int k = kc * 32 + q * 8 + j;
        float v = (k < 128) ? Wl[k * 128 + col] : Wr[(k - 128) * 128 + col];
        u16 hi, lo; split_bf(v, hi, lo);
        Bph[(long)idx * 8 + j] = hi;
        Bpl[(long)idx * 8 + j] = lo;
    }
}

// ---------------- fused GEMM + BN column stats ----------------
// out = [Al | Ar](N x 256) @ B(256 x 128) + bias; stats += {col sums, col sumsq}
// MFMA 16x16x32 bf16 split-precision: D = Ah*Bh + Ah*Bl + Al*Bh.
__global__ __launch_bounds__(256) void k_gemm(
        const float* __restrict__ Al, const float* __restrict__ Ar,
        const u16* __restrict__ Bph, const u16* __restrict__ Bpl,
        const float* __restrict__ bias,
        float* __restrict__ outH, float* __restrict__ stats, int nrows) {
    int tid = threadIdx.x;
    int wave = tid >> 6, lane = tid & 63;
    int q = lane >> 4, nn = lane & 15;
    int rowbase = blockIdx.x * 64 + wave * 16;
    int arow = rowbase + nn;
    int rclamp = (arow < nrows) ? arow : 0;

    __shared__ float smem_s[128], smem_q[128];
    if (tid < 128) { smem_s[tid] = 0.f; smem_q[tid] = 0.f; }

    f32x4 acc[8];
    #pragma unroll
    for (int i = 0; i < 8; ++i) acc[i] = (f32x4){0.f, 0.f, 0.f, 0.f};

    #pragma unroll
    for (int kc = 0; kc < 8; ++kc) {
        const float* ap = (kc < 4) ? (Al + (long)rclamp * DIM + kc * 32 + q * 8)
                                   : (Ar + (long)rclamp * DIM + (kc - 4) * 32 + q * 8);
        f32x4 a0 = *(const f32x4*)ap;
        f32x4 a1 = *(const f32x4*)(ap + 4);
        short8 ah, al;
        #pragma unroll
        for (int j = 0; j < 4; ++j) {
            u16 hi, lo;
            split_bf(a0[j], hi, lo); ah[j] = (short)hi; al[j] = (short)lo;
            split_bf(a1[j], hi, lo); ah[4 + j] = (short)hi; al[4 + j] = (short)lo;
        }
        #pragma unroll
        for (int nt = 0; nt < 8; ++nt) {
            long boff = (long)(((nt * 8 + kc) * 64 + lane)) * 8;
            short8 bh = *(const short8*)(Bph + boff);
            short8 bl = *(const short8*)(Bpl + boff);
            acc[nt] = __builtin_amdgcn_mfma_f32_16x16x32_bf16(ah, bh, acc[nt], 0, 0, 0);
            acc[nt] = __builtin_amdgcn_mfma_f32_16x16x32_bf16(ah, bl, acc[nt], 0, 0, 0);
            acc[nt] = __builtin_amdgcn_mfma_f32_16x16x32_bf16(al, bh, acc[nt], 0, 0, 0);
        }
    }

    __syncthreads();   // smem zero-init visible

    #pragma unroll
    for (int nt = 0; nt < 8; ++nt) {
        int col = nt * 16 + nn;
        float bv = bias[col];
        float ps = 0.f, pq = 0.f;
        #pragma unroll
        for (int r = 0; r < 4; ++r) {
            int orow = rowbase + q * 4 + r;
            if (orow < nrows) {
                float v = acc[nt][r] + bv;
                outH[(long)orow * DIM + col] = v;
                ps += v; pq += v * v;
            }
        }
        atomicAdd(&smem_s[col], ps);
        atomicAdd(&smem_q[col], pq);
    }
    __syncthreads();
    if (tid < 128) {
        atomicAdd(&stats[tid], smem_s[tid]);
        atomicAdd(&stats[128 + tid], smem_q[tid]);
    }
}

// ---------------- BN apply (coeff computed inline from stats) ----------------

// h = relu(h*a + b), float4; grid*256*4 == N*D exactly
__global__ __launch_bounds__(256) void k_bn_relu(
        float* __restrict__ h, const float* __restrict__ sums,
        const float* __restrict__ g, const float* __restrict__ bt) {
    long i4 = ((long)blockIdx.x * 256 + threadIdx.x) * 4;
    int c = (int)(i4 & 127);
    f32x4 hv = *(const f32x4*)(h + i4);
    f32x4 s0 = *(const f32x4*)(sums + c);
    f32x4 s1 = *(const f32x4*)(sums + 128 + c);
    f32x4 gv = *(const f32x4*)(g + c);
    f32x4 bv = *(const f32x4*)(bt + c);
    f32x4 r;
    #pragma unroll
    for (int j = 0; j < 4; ++j) {
        float mu = s0[j] * NINV;
        float var = s1[j] * NINV - mu * mu;
        float a = gv[j] * rsqrtf(var + 1e-5f);
        float v = (hv[j] - mu) * a + bv[j];
        r[j] = v > 0.f ? v : 0.f;
    }
    *(f32x4*)(h + i4) = r;
}

// out = relu(h*a + b + x), float4
__global__ __launch_bounds__(256) void k_bn_add_relu(
        const float* __restrict__ h, const float* __restrict__ sums,
        const float* __restrict__ g, const float* __restrict__ bt,
        const float* __restrict__ x, float* __restrict__ outv) {
    long i4 = ((long)blockIdx.x * 256 + threadIdx.x) * 4;
    int c = (int)(i4 & 127);
    f32x4 hv = *(const f32x4*)(h + i4);
    f32x4 xv = *(const f32x4*)(x + i4);
    f32x4 s0 = *(const f32x4*)(sums + c);
    f32x4 s1 = *(const f32x4*)(sums + 128 + c);
    f32x4 gv = *(const f32x4*)(g + c);
    f32x4 bv = *(const f32x4*)(bt + c);
    f32x4 r;
    #pragma unroll
    for (int j = 0; j < 4; ++j) {
        float mu = s0[j] * NINV;
        float var = s1[j] * NINV - mu * mu;
        float a = gv[j] * rsqrtf(var + 1e-5f);
        float v = (hv[j] - mu) * a + bv[j] + xv[j];
        r[j] = v > 0.f ? v : 0.f;
    }
    *(f32x4*)(outv + i4) = r;
}

extern "C" void kernel_launch(void* const* d_in, const int* in_sizes, int n_in,
                              void* d_out, int out_size, void* d_ws, size_t ws_size,
                              hipStream_t stream) {
    (void)in_sizes; (void)n_in; (void)out_size; (void)ws_size;
    const float* x   = (const float*)d_in[0];
    const int*   ei  = (const int*)d_in[1];
    const float* W1l = (const float*)d_in[2];
    const float* b1  = (const float*)d_in[3];
    const float* W1r = (const float*)d_in[4];
    const float* g1  = (const float*)d_in[5];
    const float* bt1 = (const float*)d_in[6];
    const float* W2l = (const float*)d_in[7];
    const float* b2  = (const float*)d_in[8];
    const float* W2r = (const float*)d_in[9];
    const float* g2  = (const float*)d_in[10];
    const float* bt2 = (const float*)d_in[11];
    float* out = (float*)d_out;

    const int* esrc = ei;
    const int* edst = ei + N_EDGES;

    char* ws = (char*)d_ws;
    size_t off = 0;
    auto alloc = [&](size_t bytes) { size_t p = off; off = (off + bytes + 255) & ~(size_t)255; return p; };
    int*   deg     = (int*)  (ws + alloc(N_NODES * 4));
    int*   cursor  = (int*)  (ws + alloc(N_NODES * 4));
    float* stats1  = (float*)(ws + alloc(256 * 4));
    float* stats2  = (float*)(ws + alloc(256 * 4));
    size_t zero_bytes = off;                       // everything above must be zeroed
    int*   row_ptr = (int*)  (ws + alloc((N_NODES + 1) * 4));
    int*   bsum    = (int*)  (ws + alloc(256 * 4));
    int*   bpre    = (int*)  (ws + alloc(256 * 4));
    int*   col_src = (int*)  (ws + alloc((size_t)N_EDGES * 4));
    float* aggbuf  = (float*)(ws + alloc((size_t)N_NODES * DIM * 4));
    float* hbuf    = (float*)(ws + alloc((size_t)N_NODES * DIM * 4));
    u16*   Bp1h    = (u16*)  (ws + alloc(256 * 128 * 2));
    u16*   Bp1l    = (u16*)  (ws + alloc(256 * 128 * 2));
    u16*   Bp2h    = (u16*)  (ws + alloc(256 * 128 * 2));
    u16*   Bp2l    = (u16*)  (ws + alloc(256 * 128 * 2));

    hipMemsetAsync(ws, 0, zero_bytes, stream);

    const int EB = (N_EDGES + 255) / 256;            // 3125
    const int GEMMB = (N_NODES + 63) / 64;           // 782
    const int AGGB = N_NODES / 8;                    // 6250 exact
    const int EWB4 = (int)(((long)N_NODES * DIM) / 1024);  // 6250 exact

    // weight packing (independent of everything else)
    k_pack_b<<<16, 256, 0, stream>>>(W1l, W1r, Bp1h, Bp1l);
    k_pack_b<<<16, 256, 0, stream>>>(W2l, W2r, Bp2h, Bp2l);

    // CSR build
    k_deg_hist<<<EB, 256, 0, stream>>>(edst, deg);
    k_scan1<<<SCAN_B, 256, 0, stream>>>(deg, bsum);
    k_scan2<<<1, 256, 0, stream>>>(bsum, bpre);
    k_scan3<<<SCAN_B, 256, 0, stream>>>(deg, bpre, row_ptr);
    k_fill<<<EB, 256, 0, stream>>>(esrc, edst, row_ptr, cursor, col_src);

    // stage 1
    k_agg<<<AGGB, 256, 0, stream>>>(x, row_ptr, col_src, aggbuf);
    k_gemm<<<GEMMB, 256, 0, stream>>>(aggbuf, x, Bp1h, Bp1l, b1, hbuf, stats1, N_NODES);
    k_bn_relu<<<EWB4, 256, 0, stream>>>(hbuf, stats1, g1, bt1);

    // stage 2 (hbuf holds h1r; gemm writes h2 in place — wave-private rows)
    k_agg<<<AGGB, 256, 0, stream>>>(hbuf, row_ptr, col_src, aggbuf);
    k_gemm<<<GEMMB, 256, 0, stream>>>(aggbuf, hbuf, Bp2h, Bp2l, b2, hbuf, stats2, N_NODES);
    k_bn_add_relu<<<EWB4, 256, 0, stream>>>(hbuf, stats2, g2, bt2, x, out);
}